// Round 1
// baseline (1194.891 us; speedup 1.0000x reference)
//
#include <hip/hip_runtime.h>
#include <math.h>

#define NB 8
#define NLQ 1024
#define NLK 1024
#define ND 512
#define NH 8
#define NDK 64
#define MASK_VALUE -1e30f

// ---------------- Projection: out[b][h][l][e] = sum_d X[b][l][d] * W[h][d][e]
// X: (B, L, D) fp32, W: (H, D, 64) fp32, out: (B, H, L, 64) fp32
// Block computes a 64(l) x 64(e) tile; 256 threads, each 4l x 4e.
__global__ __launch_bounds__(256) void proj_kernel(const float* __restrict__ X,
                                                   const float* __restrict__ W,
                                                   float* __restrict__ out) {
    __shared__ float Xs[64][36];   // 64 l x 32 d, pad to 36 (16B-aligned rows)
    __shared__ float Ws[32][64];   // 32 d x 64 e

    const int l0 = blockIdx.x * 64;
    const int h  = blockIdx.y;
    const int b  = blockIdx.z;
    const int tid = threadIdx.x;
    const int te = tid & 15;   // e-group: e = 4*te .. 4*te+3
    const int tl = tid >> 4;   // l rows: tl, tl+16, tl+32, tl+48

    float acc[4][4];
#pragma unroll
    for (int j = 0; j < 4; j++)
#pragma unroll
        for (int i = 0; i < 4; i++) acc[j][i] = 0.f;

    for (int d0 = 0; d0 < ND; d0 += 32) {
        __syncthreads();
        // X tile: 64x32 = 512 float4
#pragma unroll
        for (int i = 0; i < 2; i++) {
            int flat = tid + 256 * i;      // 0..511
            int row = flat >> 3;
            int c4  = flat & 7;
            float4 v = *(const float4*)&X[((size_t)b * NLQ + l0 + row) * ND + d0 + 4 * c4];
            *(float4*)&Xs[row][4 * c4] = v;
        }
        // W tile: 32x64 = 512 float4
#pragma unroll
        for (int i = 0; i < 2; i++) {
            int flat = tid + 256 * i;
            int row = flat >> 4;
            int c4  = flat & 15;
            float4 v = *(const float4*)&W[((size_t)h * ND + d0 + row) * 64 + 4 * c4];
            *(float4*)&Ws[row][4 * c4] = v;
        }
        __syncthreads();
#pragma unroll
        for (int dd4 = 0; dd4 < 8; dd4++) {
            float4 xv[4];
#pragma unroll
            for (int j = 0; j < 4; j++) xv[j] = *(const float4*)&Xs[tl + 16 * j][4 * dd4];
#pragma unroll
            for (int dd = 0; dd < 4; dd++) {
                float4 wv = *(const float4*)&Ws[dd4 * 4 + dd][4 * te];
#pragma unroll
                for (int j = 0; j < 4; j++) {
                    float x = (dd == 0) ? xv[j].x : (dd == 1) ? xv[j].y
                             : (dd == 2) ? xv[j].z : xv[j].w;
                    acc[j][0] += x * wv.x;
                    acc[j][1] += x * wv.y;
                    acc[j][2] += x * wv.z;
                    acc[j][3] += x * wv.w;
                }
            }
        }
    }
#pragma unroll
    for (int j = 0; j < 4; j++) {
        int l = l0 + tl + 16 * j;
        float4 v = make_float4(acc[j][0], acc[j][1], acc[j][2], acc[j][3]);
        *(float4*)&out[(((size_t)b * NH + h) * NLQ + l) * 64 + 4 * te] = v;
    }
}

// ---------------- Flash attention (fp32). One thread owns one q row.
// Qp/Kp/Vp: (B,H,L,64). Output written in conc layout: (B, LQ, H, 64).
__global__ __launch_bounds__(256) void attn_kernel(const float* __restrict__ Qp,
                                                   const float* __restrict__ Kp,
                                                   const float* __restrict__ Vp,
                                                   const float* __restrict__ maskp,
                                                   float* __restrict__ Op) {
    const int qc = blockIdx.x;  // 0..3
    const int h  = blockIdx.y;
    const int b  = blockIdx.z;
    const int tid = threadIdx.x;
    const int q = qc * 256 + tid;
    const size_t bh = (size_t)b * NH + h;

    float4 qv[16];
    {
        const float* qrow = &Qp[(bh * NLQ + q) * 64];
#pragma unroll
        for (int i = 0; i < 16; i++) qv[i] = *(const float4*)&qrow[4 * i];
    }
    float4 ov[16];
#pragma unroll
    for (int i = 0; i < 16; i++) ov[i] = make_float4(0.f, 0.f, 0.f, 0.f);
    float mrun = MASK_VALUE;
    float lrun = 0.f;

    __shared__ float Ks[64][64];
    __shared__ float Vs[64][64];
    __shared__ float Ms[64];

    for (int k0 = 0; k0 < NLK; k0 += 64) {
        __syncthreads();
#pragma unroll
        for (int i = 0; i < 4; i++) {
            int flat = tid + 256 * i;   // 0..1023
            int row = flat >> 4;
            int c4  = flat & 15;
            *(float4*)&Ks[row][4 * c4] =
                *(const float4*)&Kp[(bh * NLK + k0 + row) * 64 + 4 * c4];
            *(float4*)&Vs[row][4 * c4] =
                *(const float4*)&Vp[(bh * NLK + k0 + row) * 64 + 4 * c4];
        }
        if (tid < 64) Ms[tid] = maskp[(size_t)b * NLK + k0 + tid];
        __syncthreads();

#pragma unroll 1
        for (int kk0 = 0; kk0 < 64; kk0 += 8) {
            float s[8];
#pragma unroll
            for (int j = 0; j < 8; j++) {
                float4 a4 = make_float4(0.f, 0.f, 0.f, 0.f);
#pragma unroll
                for (int i = 0; i < 16; i++) {
                    float4 kv = *(const float4*)&Ks[kk0 + j][4 * i];
                    a4.x += qv[i].x * kv.x;
                    a4.y += qv[i].y * kv.y;
                    a4.z += qv[i].z * kv.z;
                    a4.w += qv[i].w * kv.w;
                }
                float sv = (a4.x + a4.y) + (a4.z + a4.w);
                float mval = Ms[kk0 + j];
                s[j] = mval * sv + (1.f - mval) * MASK_VALUE;  // exact ref semantics
            }
            float tm = s[0];
#pragma unroll
            for (int j = 1; j < 8; j++) tm = fmaxf(tm, s[j]);
            float newm = fmaxf(mrun, tm);
            float alpha = __expf(mrun - newm);
            mrun = newm;
            lrun *= alpha;
#pragma unroll
            for (int i = 0; i < 16; i++) {
                ov[i].x *= alpha; ov[i].y *= alpha;
                ov[i].z *= alpha; ov[i].w *= alpha;
            }
#pragma unroll
            for (int j = 0; j < 8; j++) {
                float p = __expf(s[j] - mrun);
                lrun += p;
#pragma unroll
                for (int i = 0; i < 16; i++) {
                    float4 vv = *(const float4*)&Vs[kk0 + j][4 * i];
                    ov[i].x += p * vv.x;
                    ov[i].y += p * vv.y;
                    ov[i].z += p * vv.z;
                    ov[i].w += p * vv.w;
                }
            }
        }
    }
    const float inv = 1.f / lrun;
    float* orow = &Op[(((size_t)b * NLQ + q) * NH + h) * 64];  // conc layout
#pragma unroll
    for (int i = 0; i < 16; i++) {
        float4 v = make_float4(ov[i].x * inv, ov[i].y * inv, ov[i].z * inv, ov[i].w * inv);
        *(float4*)&orow[4 * i] = v;
    }
}

// ---------------- LayerNorm over last dim (512), in-place safe.
// One wave per row; 4 rows per 256-thread block.
__global__ __launch_bounds__(256) void ln_kernel(const float* __restrict__ X,
                                                 const float* __restrict__ gamma,
                                                 const float* __restrict__ beta,
                                                 float* __restrict__ out) {
    const int row = blockIdx.x * 4 + (threadIdx.x >> 6);
    const int lane = threadIdx.x & 63;
    const float* x = &X[(size_t)row * 512];
    float4 v0 = *(const float4*)&x[lane * 8];
    float4 v1 = *(const float4*)&x[lane * 8 + 4];
    float sum = v0.x + v0.y + v0.z + v0.w + v1.x + v1.y + v1.z + v1.w;
    float sq = v0.x * v0.x + v0.y * v0.y + v0.z * v0.z + v0.w * v0.w
             + v1.x * v1.x + v1.y * v1.y + v1.z * v1.z + v1.w * v1.w;
#pragma unroll
    for (int off = 32; off > 0; off >>= 1) {
        sum += __shfl_down(sum, off);
        sq  += __shfl_down(sq, off);
    }
    sum = __shfl(sum, 0);
    sq  = __shfl(sq, 0);
    const float mean = sum * (1.f / 512.f);
    const float var = sq * (1.f / 512.f) - mean * mean;
    const float rstd = rsqrtf(var + 1e-14f);
    const float g = gamma[0], be = beta[0];
    float* o = &out[(size_t)row * 512];
    float4 r0, r1;
    r0.x = (v0.x - mean) * rstd * g + be;  r0.y = (v0.y - mean) * rstd * g + be;
    r0.z = (v0.z - mean) * rstd * g + be;  r0.w = (v0.w - mean) * rstd * g + be;
    r1.x = (v1.x - mean) * rstd * g + be;  r1.y = (v1.y - mean) * rstd * g + be;
    r1.z = (v1.z - mean) * rstd * g + be;  r1.w = (v1.w - mean) * rstd * g + be;
    *(float4*)&o[lane * 8] = r0;
    *(float4*)&o[lane * 8 + 4] = r1;
}

extern "C" void kernel_launch(void* const* d_in, const int* in_sizes, int n_in,
                              void* d_out, int out_size, void* d_ws, size_t ws_size,
                              hipStream_t stream) {
    const float* query = (const float*)d_in[0];
    const float* key_t = (const float*)d_in[1];
    const float* value = (const float*)d_in[2];
    const float* mask  = (const float*)d_in[3];
    const float* Wq    = (const float*)d_in[4];
    const float* Wk    = (const float*)d_in[5];
    const float* Wv    = (const float*)d_in[6];
    const float* gamma = (const float*)d_in[7];
    const float* beta  = (const float*)d_in[8];
    float* out = (float*)d_out;

    const size_t per = (size_t)NB * NH * NLQ * 64;  // 4,194,304 floats
    float* Qp = (float*)d_ws;
    float* Kp = Qp + per;
    float* Vp = Kp + per;

    dim3 pgrid(NLQ / 64, NH, NB);
    proj_kernel<<<pgrid, 256, 0, stream>>>(query, Wq, Qp);
    proj_kernel<<<pgrid, 256, 0, stream>>>(key_t, Wk, Kp);
    proj_kernel<<<pgrid, 256, 0, stream>>>(value, Wv, Vp);

    dim3 agrid(NLQ / 256, NH, NB);
    attn_kernel<<<agrid, 256, 0, stream>>>(Qp, Kp, Vp, mask, out);

    ln_kernel<<<(NB * NLQ) / 4, 256, 0, stream>>>(out, gamma, beta, out);
}

// Round 2
// 328.167 us; speedup vs baseline: 3.6411x; 3.6411x over previous
//
#include <hip/hip_runtime.h>
#include <math.h>

#define NB 8
#define NLQ 1024
#define NLK 1024
#define ND 512
#define NH 8
#define MASKV -1e30f

typedef unsigned short ushort_t;
typedef __attribute__((ext_vector_type(8))) short bf16x8;
typedef __attribute__((ext_vector_type(16))) float f32x16;

__device__ __forceinline__ ushort_t f2bf(float f) {
    union { float f; unsigned u; } v; v.f = f;
    unsigned r = v.u + 0x7fffu + ((v.u >> 16) & 1u);
    return (ushort_t)(r >> 16);
}
__device__ __forceinline__ float bf2f(ushort_t h) {
    union { unsigned u; float f; } v; v.u = ((unsigned)h) << 16;
    return v.f;
}

// ---------------- Projection: out[b][h][l][e] = sum_d X[b][l][d] * W[h][d][e]
// MODE 0: write hi+lo bf16 split arrays, layout (b,h,l,64)    [for Q, K]
// MODE 1: write single bf16 TRANSPOSED array, layout (b,h,e,l) [for V]
template <int MODE>
__global__ __launch_bounds__(256) void proj_kernel(const float* __restrict__ X,
                                                   const float* __restrict__ W,
                                                   ushort_t* __restrict__ out_hi,
                                                   ushort_t* __restrict__ out_lo) {
    __shared__ float Xs[64][36];   // 64 l x 32 d (pad to 36)
    __shared__ float Ws[32][64];   // 32 d x 64 e
    __shared__ float T[64][68];    // transpose staging (MODE 1 epilogue)

    const int l0 = blockIdx.x * 64;
    const int h  = blockIdx.y;
    const int b  = blockIdx.z;
    const int tid = threadIdx.x;
    const int te = tid & 15;   // e = 4*te .. 4*te+3
    const int tl = tid >> 4;   // l rows: tl, tl+16, tl+32, tl+48
    const size_t bh = (size_t)b * NH + h;

    float acc[4][4];
#pragma unroll
    for (int j = 0; j < 4; j++)
#pragma unroll
        for (int i = 0; i < 4; i++) acc[j][i] = 0.f;

    for (int d0 = 0; d0 < ND; d0 += 32) {
        __syncthreads();
#pragma unroll
        for (int i = 0; i < 2; i++) {
            int flat = tid + 256 * i;      // 0..511
            int row = flat >> 3;
            int c4  = flat & 7;
            float4 v = *(const float4*)&X[((size_t)b * NLQ + l0 + row) * ND + d0 + 4 * c4];
            *(float4*)&Xs[row][4 * c4] = v;
        }
#pragma unroll
        for (int i = 0; i < 2; i++) {
            int flat = tid + 256 * i;
            int row = flat >> 4;
            int c4  = flat & 15;
            float4 v = *(const float4*)&W[((size_t)h * ND + d0 + row) * 64 + 4 * c4];
            *(float4*)&Ws[row][4 * c4] = v;
        }
        __syncthreads();
#pragma unroll
        for (int dd4 = 0; dd4 < 8; dd4++) {
            float4 xv[4];
#pragma unroll
            for (int j = 0; j < 4; j++) xv[j] = *(const float4*)&Xs[tl + 16 * j][4 * dd4];
#pragma unroll
            for (int dd = 0; dd < 4; dd++) {
                float4 wv = *(const float4*)&Ws[dd4 * 4 + dd][4 * te];
#pragma unroll
                for (int j = 0; j < 4; j++) {
                    float x = (dd == 0) ? xv[j].x : (dd == 1) ? xv[j].y
                             : (dd == 2) ? xv[j].z : xv[j].w;
                    acc[j][0] += x * wv.x;
                    acc[j][1] += x * wv.y;
                    acc[j][2] += x * wv.z;
                    acc[j][3] += x * wv.w;
                }
            }
        }
    }

    if (MODE == 0) {
        // hi/lo bf16 split, layout (b,h,l,64)
#pragma unroll
        for (int j = 0; j < 4; j++) {
            int l = l0 + tl + 16 * j;
            ushort_t h0[4], lo0[4];
#pragma unroll
            for (int i = 0; i < 4; i++) {
                float f = acc[j][i];
                h0[i] = f2bf(f);
                lo0[i] = f2bf(f - bf2f(h0[i]));
            }
            uint2 wh, wl;
            wh.x = (unsigned)h0[0] | ((unsigned)h0[1] << 16);
            wh.y = (unsigned)h0[2] | ((unsigned)h0[3] << 16);
            wl.x = (unsigned)lo0[0] | ((unsigned)lo0[1] << 16);
            wl.y = (unsigned)lo0[2] | ((unsigned)lo0[3] << 16);
            size_t base = (bh * NLQ + l) * 64 + 4 * te;
            *(uint2*)&out_hi[base] = wh;
            *(uint2*)&out_lo[base] = wl;
        }
    } else {
        // transpose via LDS, write bf16 (b,h,e,l)
        __syncthreads();
#pragma unroll
        for (int j = 0; j < 4; j++)
#pragma unroll
            for (int i = 0; i < 4; i++)
                T[4 * te + i][tl + 16 * j] = acc[j][i];
        __syncthreads();
        const int e = tid >> 2;          // 0..63
        const int c0 = (tid & 3) * 16;   // 0,16,32,48
        ushort_t ob[16];
#pragma unroll
        for (int c = 0; c < 4; c++) {
            float4 v = *(const float4*)&T[e][c0 + 4 * c];
            ob[4 * c + 0] = f2bf(v.x); ob[4 * c + 1] = f2bf(v.y);
            ob[4 * c + 2] = f2bf(v.z); ob[4 * c + 3] = f2bf(v.w);
        }
        size_t base = (bh * 64 + e) * NLK + l0 + c0;
        uint4 w0, w1;
        w0.x = (unsigned)ob[0] | ((unsigned)ob[1] << 16);
        w0.y = (unsigned)ob[2] | ((unsigned)ob[3] << 16);
        w0.z = (unsigned)ob[4] | ((unsigned)ob[5] << 16);
        w0.w = (unsigned)ob[6] | ((unsigned)ob[7] << 16);
        w1.x = (unsigned)ob[8] | ((unsigned)ob[9] << 16);
        w1.y = (unsigned)ob[10] | ((unsigned)ob[11] << 16);
        w1.z = (unsigned)ob[12] | ((unsigned)ob[13] << 16);
        w1.w = (unsigned)ob[14] | ((unsigned)ob[15] << 16);
        *(uint4*)&out_hi[base] = w0;
        *(uint4*)&out_hi[base + 8] = w1;
    }
}

// ---------------- MFMA flash attention.
// S^T = K·Q^T (bf16x2: 3 MFMAs), softmax lane-local (col=q), O^T = V^T·P^T.
// Block: 4 waves, each wave 32 q. Q-tile 128. Output in conc layout (b,q,h*64+e), fp32.
__global__ __launch_bounds__(256, 3) void attn_kernel(
    const ushort_t* __restrict__ Qhi, const ushort_t* __restrict__ Qlo,
    const ushort_t* __restrict__ Khi, const ushort_t* __restrict__ Klo,
    const ushort_t* __restrict__ Vt,  const float* __restrict__ maskp,
    float* __restrict__ Op) {
    __shared__ ushort_t sKh[64][72];
    __shared__ ushort_t sKl[64][72];
    __shared__ ushort_t sVt[64][72];   // sVt[e][key]
    __shared__ float sBs[64];
    __shared__ ushort_t sPs[4][32][72];  // per-wave P (q x key)

    const int tid  = threadIdx.x;
    const int wave = tid >> 6;
    const int lane = tid & 63;
    const int l31  = lane & 31;
    const int hib  = lane >> 5;     // 0/1
    const int h = blockIdx.y, b = blockIdx.z;
    const size_t bh = (size_t)b * NH + h;
    const int q = blockIdx.x * 128 + wave * 32 + l31;

    // Q fragments (B-operand of S^T): B[k=e][n=q], e = 8*hib + j + 16*c
    bf16x8 qh[4], ql[4];
    {
        const ushort_t* ph = Qhi + (bh * NLQ + q) * 64 + hib * 8;
        const ushort_t* pl = Qlo + (bh * NLQ + q) * 64 + hib * 8;
#pragma unroll
        for (int c = 0; c < 4; c++) {
            qh[c] = *(const bf16x8*)(ph + c * 16);
            ql[c] = *(const bf16x8*)(pl + c * 16);
        }
    }

    f32x16 O0, O1;
#pragma unroll
    for (int i = 0; i < 16; i++) { O0[i] = 0.f; O1[i] = 0.f; }
    float mrun = MASKV, lrun = 0.f;

    const int skey = tid >> 2;          // 0..63 (also e-row for V staging)
    const int se0  = (tid & 3) * 16;    // 0,16,32,48

    for (int k0 = 0; k0 < NLK; k0 += 64) {
        __syncthreads();
        {
            const ushort_t* src = Khi + ((bh << 10) + k0 + skey) * 64 + se0;
            *(uint4*)&sKh[skey][se0]     = *(const uint4*)src;
            *(uint4*)&sKh[skey][se0 + 8] = *(const uint4*)(src + 8);
            const ushort_t* srl = Klo + ((bh << 10) + k0 + skey) * 64 + se0;
            *(uint4*)&sKl[skey][se0]     = *(const uint4*)srl;
            *(uint4*)&sKl[skey][se0 + 8] = *(const uint4*)(srl + 8);
            const ushort_t* srv = Vt + ((bh << 6) + skey) * NLK + k0 + se0;
            *(uint4*)&sVt[skey][se0]     = *(const uint4*)srv;
            *(uint4*)&sVt[skey][se0 + 8] = *(const uint4*)(srv + 8);
            if (tid < 64) sBs[tid] = (1.f - maskp[(b << 10) + k0 + tid]) * MASKV;
        }
        __syncthreads();

        // S^T = K · Q^T  (A = K rows from LDS, B = Q frags in regs)
        f32x16 S0, S1;
#pragma unroll
        for (int i = 0; i < 16; i++) { S0[i] = 0.f; S1[i] = 0.f; }
#pragma unroll
        for (int c = 0; c < 4; c++) {
            bf16x8 ah0 = *(const bf16x8*)&sKh[l31][c * 16 + hib * 8];
            bf16x8 al0 = *(const bf16x8*)&sKl[l31][c * 16 + hib * 8];
            bf16x8 ah1 = *(const bf16x8*)&sKh[32 + l31][c * 16 + hib * 8];
            bf16x8 al1 = *(const bf16x8*)&sKl[32 + l31][c * 16 + hib * 8];
            S0 = __builtin_amdgcn_mfma_f32_32x32x16_bf16(ah0, qh[c], S0, 0, 0, 0);
            S1 = __builtin_amdgcn_mfma_f32_32x32x16_bf16(ah1, qh[c], S1, 0, 0, 0);
            S0 = __builtin_amdgcn_mfma_f32_32x32x16_bf16(ah0, ql[c], S0, 0, 0, 0);
            S1 = __builtin_amdgcn_mfma_f32_32x32x16_bf16(ah1, ql[c], S1, 0, 0, 0);
            S0 = __builtin_amdgcn_mfma_f32_32x32x16_bf16(al0, qh[c], S0, 0, 0, 0);
            S1 = __builtin_amdgcn_mfma_f32_32x32x16_bf16(al1, qh[c], S1, 0, 0, 0);
        }

        // add mask bias: row key = 32*kh + 8*g + rr + 4*hib, col q = l31 (lane-local!)
#pragma unroll
        for (int g = 0; g < 4; g++) {
            float4 b0 = *(const float4*)&sBs[hib * 4 + 8 * g];
            float4 b1 = *(const float4*)&sBs[32 + hib * 4 + 8 * g];
            S0[4 * g + 0] += b0.x; S0[4 * g + 1] += b0.y;
            S0[4 * g + 2] += b0.z; S0[4 * g + 3] += b0.w;
            S1[4 * g + 0] += b1.x; S1[4 * g + 1] += b1.y;
            S1[4 * g + 2] += b1.z; S1[4 * g + 3] += b1.w;
        }

        // online softmax, lane-local q; other half of keys lives in lane^32
        float mloc = S0[0];
#pragma unroll
        for (int i = 1; i < 16; i++) mloc = fmaxf(mloc, S0[i]);
#pragma unroll
        for (int i = 0; i < 16; i++) mloc = fmaxf(mloc, S1[i]);
        mloc = fmaxf(mloc, __shfl_xor(mloc, 32));
        float newm = fmaxf(mrun, mloc);
        float alpha = __expf(mrun - newm);
        mrun = newm;

        float ls = 0.f;
#pragma unroll
        for (int kh = 0; kh < 2; kh++) {
#pragma unroll
            for (int g = 0; g < 4; g++) {
                float p0, p1, p2, p3;
                if (kh == 0) {
                    p0 = __expf(S0[4 * g + 0] - newm); p1 = __expf(S0[4 * g + 1] - newm);
                    p2 = __expf(S0[4 * g + 2] - newm); p3 = __expf(S0[4 * g + 3] - newm);
                } else {
                    p0 = __expf(S1[4 * g + 0] - newm); p1 = __expf(S1[4 * g + 1] - newm);
                    p2 = __expf(S1[4 * g + 2] - newm); p3 = __expf(S1[4 * g + 3] - newm);
                }
                ls += (p0 + p1) + (p2 + p3);
                uint2 w;
                w.x = (unsigned)f2bf(p0) | ((unsigned)f2bf(p1) << 16);
                w.y = (unsigned)f2bf(p2) | ((unsigned)f2bf(p3) << 16);
                *(uint2*)&sPs[wave][l31][kh * 32 + 8 * g + 4 * hib] = w;
            }
        }
        ls += __shfl_xor(ls, 32);
        lrun = lrun * alpha + ls;
#pragma unroll
        for (int i = 0; i < 16; i++) { O0[i] *= alpha; O1[i] *= alpha; }

        // O^T += V^T · P^T : A = V^T rows (e), B = P^T (n=q), both b128 from LDS
#pragma unroll
        for (int c = 0; c < 4; c++) {
            bf16x8 pf = *(const bf16x8*)&sPs[wave][l31][c * 16 + hib * 8];
            bf16x8 v0 = *(const bf16x8*)&sVt[l31][c * 16 + hib * 8];
            bf16x8 v1 = *(const bf16x8*)&sVt[32 + l31][c * 16 + hib * 8];
            O0 = __builtin_amdgcn_mfma_f32_32x32x16_bf16(v0, pf, O0, 0, 0, 0);
            O1 = __builtin_amdgcn_mfma_f32_32x32x16_bf16(v1, pf, O1, 0, 0, 0);
        }
    }

    const float linv = 1.f / lrun;
    float* obase = Op + ((size_t)(b * NLQ + q)) * (NH * 64) + h * 64;
#pragma unroll
    for (int me = 0; me < 2; me++) {
#pragma unroll
        for (int g = 0; g < 4; g++) {
            int e0 = me * 32 + 8 * g + 4 * hib;
            float4 o;
            if (me == 0) {
                o.x = O0[4 * g + 0] * linv; o.y = O0[4 * g + 1] * linv;
                o.z = O0[4 * g + 2] * linv; o.w = O0[4 * g + 3] * linv;
            } else {
                o.x = O1[4 * g + 0] * linv; o.y = O1[4 * g + 1] * linv;
                o.z = O1[4 * g + 2] * linv; o.w = O1[4 * g + 3] * linv;
            }
            *(float4*)&obase[e0] = o;
        }
    }
}

// ---------------- LayerNorm over last dim (512), in-place safe.
__global__ __launch_bounds__(256) void ln_kernel(const float* __restrict__ X,
                                                 const float* __restrict__ gamma,
                                                 const float* __restrict__ beta,
                                                 float* __restrict__ out) {
    const int row = blockIdx.x * 4 + (threadIdx.x >> 6);
    const int lane = threadIdx.x & 63;
    const float* x = &X[(size_t)row * 512];
    float4 v0 = *(const float4*)&x[lane * 8];
    float4 v1 = *(const float4*)&x[lane * 8 + 4];
    float sum = v0.x + v0.y + v0.z + v0.w + v1.x + v1.y + v1.z + v1.w;
    float sq = v0.x * v0.x + v0.y * v0.y + v0.z * v0.z + v0.w * v0.w
             + v1.x * v1.x + v1.y * v1.y + v1.z * v1.z + v1.w * v1.w;
#pragma unroll
    for (int off = 32; off > 0; off >>= 1) {
        sum += __shfl_down(sum, off);
        sq  += __shfl_down(sq, off);
    }
    sum = __shfl(sum, 0);
    sq  = __shfl(sq, 0);
    const float mean = sum * (1.f / 512.f);
    const float var = sq * (1.f / 512.f) - mean * mean;
    const float rstd = rsqrtf(var + 1e-14f);
    const float g = gamma[0], be = beta[0];
    float* o = &out[(size_t)row * 512];
    float4 r0, r1;
    r0.x = (v0.x - mean) * rstd * g + be;  r0.y = (v0.y - mean) * rstd * g + be;
    r0.z = (v0.z - mean) * rstd * g + be;  r0.w = (v0.w - mean) * rstd * g + be;
    r1.x = (v1.x - mean) * rstd * g + be;  r1.y = (v1.y - mean) * rstd * g + be;
    r1.z = (v1.z - mean) * rstd * g + be;  r1.w = (v1.w - mean) * rstd * g + be;
    *(float4*)&o[lane * 8] = r0;
    *(float4*)&o[lane * 8 + 4] = r1;
}

extern "C" void kernel_launch(void* const* d_in, const int* in_sizes, int n_in,
                              void* d_out, int out_size, void* d_ws, size_t ws_size,
                              hipStream_t stream) {
    const float* query = (const float*)d_in[0];
    const float* key_t = (const float*)d_in[1];
    const float* value = (const float*)d_in[2];
    const float* mask  = (const float*)d_in[3];
    const float* Wq    = (const float*)d_in[4];
    const float* Wk    = (const float*)d_in[5];
    const float* Wv    = (const float*)d_in[6];
    const float* gamma = (const float*)d_in[7];
    const float* beta  = (const float*)d_in[8];
    float* out = (float*)d_out;

    const size_t A = (size_t)NB * NH * NLQ * 64;  // 4,194,304 elems
    ushort_t* Qhi = (ushort_t*)d_ws;
    ushort_t* Qlo = Qhi + A;
    ushort_t* KhiG = Qhi + 2 * A;
    ushort_t* KloG = Qhi + 3 * A;
    ushort_t* VtG  = Qhi + 4 * A;

    dim3 pgrid(NLQ / 64, NH, NB);
    proj_kernel<0><<<pgrid, 256, 0, stream>>>(query, Wq, Qhi, Qlo);
    proj_kernel<0><<<pgrid, 256, 0, stream>>>(key_t, Wk, KhiG, KloG);
    proj_kernel<1><<<pgrid, 256, 0, stream>>>(value, Wv, VtG, nullptr);

    dim3 agrid(NLQ / 128, NH, NB);
    attn_kernel<<<agrid, 256, 0, stream>>>(Qhi, Qlo, KhiG, KloG, VtG, mask, out);

    ln_kernel<<<(NB * NLQ) / 4, 256, 0, stream>>>(out, gamma, beta, out);
}

// Round 3
// 223.197 us; speedup vs baseline: 5.3535x; 1.4703x over previous
//
#include <hip/hip_runtime.h>
#include <math.h>

#define NB 8
#define NLQ 1024
#define NLK 1024
#define ND 512
#define NH 8
#define MASKV -1e30f

typedef unsigned short ushort_t;
typedef __attribute__((ext_vector_type(8))) short bf16x8;
typedef __attribute__((ext_vector_type(16))) float f32x16;

__device__ __forceinline__ ushort_t f2bf(float f) {
    union { float f; unsigned u; } v; v.f = f;
    unsigned r = v.u + 0x7fffu + ((v.u >> 16) & 1u);
    return (ushort_t)(r >> 16);
}
__device__ __forceinline__ float bf2f(ushort_t h) {
    union { unsigned u; float f; } v; v.u = ((unsigned)h) << 16;
    return v.f;
}
__device__ __forceinline__ void gload16(const ushort_t* g, ushort_t* l) {
    __builtin_amdgcn_global_load_lds(
        (const __attribute__((address_space(1))) void*)g,
        (__attribute__((address_space(3))) void*)l, 16, 0, 0);
}

// ---------------- W transpose+split: W (H,512,64) fp32 -> Wt (H,64,512) bf16 hi/lo
__global__ __launch_bounds__(256) void wsplit_kernel(
    const float* __restrict__ Wq, const float* __restrict__ Wk, const float* __restrict__ Wv,
    ushort_t* __restrict__ qh, ushort_t* __restrict__ ql,
    ushort_t* __restrict__ kh, ushort_t* __restrict__ kl,
    ushort_t* __restrict__ vh, ushort_t* __restrict__ vl) {
    __shared__ float T[64][65];
    const int d0 = blockIdx.x * 64;
    const int h  = blockIdx.y;
    const int t  = blockIdx.z;
    const float* W = (t == 0) ? Wq : (t == 1) ? Wk : Wv;
    ushort_t* oh = (t == 0) ? qh : (t == 1) ? kh : vh;
    ushort_t* ol = (t == 0) ? ql : (t == 1) ? kl : vl;
    const int tid = threadIdx.x;
#pragma unroll
    for (int i = 0; i < 4; i++) {
        int r = (tid >> 4) + i * 16;
        int c = (tid & 15) * 4;
        float4 v = *(const float4*)&W[((size_t)h * ND + d0 + r) * 64 + c];
        *(float4*)&T[r][c] = v;
    }
    __syncthreads();
    const int e = tid & 63;
    const int dg = tid >> 6;  // 0..3, 16 d each
    ushort_t hs[16], ls[16];
#pragma unroll
    for (int dd = 0; dd < 16; dd++) {
        float f = T[dg * 16 + dd][e];
        hs[dd] = f2bf(f);
        ls[dd] = f2bf(f - bf2f(hs[dd]));
    }
    size_t base = ((size_t)h * 64 + e) * ND + d0 + dg * 16;
#pragma unroll
    for (int c = 0; c < 2; c++) {
        uint4 wh, wl;
        wh.x = (unsigned)hs[8*c+0] | ((unsigned)hs[8*c+1] << 16);
        wh.y = (unsigned)hs[8*c+2] | ((unsigned)hs[8*c+3] << 16);
        wh.z = (unsigned)hs[8*c+4] | ((unsigned)hs[8*c+5] << 16);
        wh.w = (unsigned)hs[8*c+6] | ((unsigned)hs[8*c+7] << 16);
        wl.x = (unsigned)ls[8*c+0] | ((unsigned)ls[8*c+1] << 16);
        wl.y = (unsigned)ls[8*c+2] | ((unsigned)ls[8*c+3] << 16);
        wl.z = (unsigned)ls[8*c+4] | ((unsigned)ls[8*c+5] << 16);
        wl.w = (unsigned)ls[8*c+6] | ((unsigned)ls[8*c+7] << 16);
        *(uint4*)&oh[base + 8 * c] = wh;
        *(uint4*)&ol[base + 8 * c] = wl;
    }
}

// ---------------- X split: fp32 (B,L,512) -> hi/lo bf16 same layout
template <int WRITE_LO>
__global__ __launch_bounds__(256) void xsplit_kernel(const float* __restrict__ X,
                                                     ushort_t* __restrict__ hi,
                                                     ushort_t* __restrict__ lo) {
    const size_t i = ((size_t)blockIdx.x * 256 + threadIdx.x) * 8;
    float4 a = *(const float4*)&X[i];
    float4 b = *(const float4*)&X[i + 4];
    float f[8] = {a.x, a.y, a.z, a.w, b.x, b.y, b.z, b.w};
    ushort_t hs[8], ls[8];
#pragma unroll
    for (int j = 0; j < 8; j++) {
        hs[j] = f2bf(f[j]);
        ls[j] = f2bf(f[j] - bf2f(hs[j]));
    }
    uint4 wh;
    wh.x = (unsigned)hs[0] | ((unsigned)hs[1] << 16);
    wh.y = (unsigned)hs[2] | ((unsigned)hs[3] << 16);
    wh.z = (unsigned)hs[4] | ((unsigned)hs[5] << 16);
    wh.w = (unsigned)hs[6] | ((unsigned)hs[7] << 16);
    *(uint4*)&hi[i] = wh;
    if (WRITE_LO) {
        uint4 wl;
        wl.x = (unsigned)ls[0] | ((unsigned)ls[1] << 16);
        wl.y = (unsigned)ls[2] | ((unsigned)ls[3] << 16);
        wl.z = (unsigned)ls[4] | ((unsigned)ls[5] << 16);
        wl.w = (unsigned)ls[6] | ((unsigned)ls[7] << 16);
        *(uint4*)&lo[i] = wl;
    }
}

// ---------------- MFMA projection.
// NSPLIT=3: acc = XhWh + XhWl + XlWh (Q,K). NSPLIT=1: XhWh (V).
// MODE 0: write hi/lo split (b,h,l,64). MODE 1: write bf16 transposed (b,h,e,l).
// Tile: 128 l x 64 e, BK=64, 4 waves. XOR-swizzled LDS (16B chunk j ^= row&7).
template <int NSPLIT, int MODE>
__global__ __launch_bounds__(256) void proj_mfma_kernel(
    const ushort_t* __restrict__ Xh, const ushort_t* __restrict__ Xl,
    const ushort_t* __restrict__ Wh, const ushort_t* __restrict__ Wl,
    ushort_t* __restrict__ out_hi, ushort_t* __restrict__ out_lo) {
    __shared__ union {
        struct { ushort_t Xh[128 * 64], Xl[128 * 64], Wh[64 * 64], Wl[64 * 64]; } s;
        ushort_t T[64][136];
    } u;

    const int l0 = blockIdx.x * 128;
    const int h  = blockIdx.y;
    const int b  = blockIdx.z;
    const int tid  = threadIdx.x;
    const int wave = tid >> 6;
    const int lane = tid & 63;
    const int l31  = lane & 31;
    const int hib  = lane >> 5;
    const size_t bh = (size_t)b * NH + h;

    const ushort_t* gxh = Xh + ((size_t)b * NLQ + l0) * ND;
    const ushort_t* gxl = Xl + ((size_t)b * NLQ + l0) * ND;
    const ushort_t* gwh = Wh + (size_t)h * 64 * ND;
    const ushort_t* gwl = Wl + (size_t)h * 64 * ND;

    f32x16 acc0, acc1;
#pragma unroll
    for (int i = 0; i < 16; i++) { acc0[i] = 0.f; acc1[i] = 0.f; }

    const int rm = wave * 32 + l31;   // A row (l)
    const int sw = l31 & 7;           // swizzle key (same for A and B rows)

    for (int kc = 0; kc < ND / 64; kc++) {
        const int d0 = kc * 64;
        __syncthreads();
        // stage X tile(s): 128 rows x 8 chunks = 1024 slots
#pragma unroll
        for (int i = 0; i < 4; i++) {
            int s = i * 256 + wave * 64;
            int sl = s + lane;
            int row = sl >> 3;
            int j = (sl & 7) ^ (row & 7);
            gload16(gxh + (size_t)row * ND + d0 + j * 8, u.s.Xh + s * 8);
            if (NSPLIT == 3)
                gload16(gxl + (size_t)row * ND + d0 + j * 8, u.s.Xl + s * 8);
        }
        // stage W tile(s): 64 rows x 8 chunks = 512 slots
#pragma unroll
        for (int i = 0; i < 2; i++) {
            int s = i * 256 + wave * 64;
            int sl = s + lane;
            int e = sl >> 3;
            int j = (sl & 7) ^ (e & 7);
            gload16(gwh + (size_t)e * ND + d0 + j * 8, u.s.Wh + s * 8);
            if (NSPLIT == 3)
                gload16(gwl + (size_t)e * ND + d0 + j * 8, u.s.Wl + s * 8);
        }
        __syncthreads();
#pragma unroll
        for (int t = 0; t < 4; t++) {
            const int j = (2 * t + hib) ^ sw;
            bf16x8 xh = *(const bf16x8*)&u.s.Xh[rm * 64 + j * 8];
            bf16x8 wh0 = *(const bf16x8*)&u.s.Wh[l31 * 64 + j * 8];
            bf16x8 wh1 = *(const bf16x8*)&u.s.Wh[(32 + l31) * 64 + j * 8];
            acc0 = __builtin_amdgcn_mfma_f32_32x32x16_bf16(xh, wh0, acc0, 0, 0, 0);
            acc1 = __builtin_amdgcn_mfma_f32_32x32x16_bf16(xh, wh1, acc1, 0, 0, 0);
            if (NSPLIT == 3) {
                bf16x8 xl = *(const bf16x8*)&u.s.Xl[rm * 64 + j * 8];
                bf16x8 wl0 = *(const bf16x8*)&u.s.Wl[l31 * 64 + j * 8];
                bf16x8 wl1 = *(const bf16x8*)&u.s.Wl[(32 + l31) * 64 + j * 8];
                acc0 = __builtin_amdgcn_mfma_f32_32x32x16_bf16(xh, wl0, acc0, 0, 0, 0);
                acc1 = __builtin_amdgcn_mfma_f32_32x32x16_bf16(xh, wl1, acc1, 0, 0, 0);
                acc0 = __builtin_amdgcn_mfma_f32_32x32x16_bf16(xl, wh0, acc0, 0, 0, 0);
                acc1 = __builtin_amdgcn_mfma_f32_32x32x16_bf16(xl, wh1, acc1, 0, 0, 0);
            }
        }
    }

    if (MODE == 0) {
        const size_t obase = (bh * NLQ + l0) * 64;
#pragma unroll
        for (int nt = 0; nt < 2; nt++) {
            const int e = nt * 32 + l31;
            const f32x16& A = nt ? acc1 : acc0;
#pragma unroll
            for (int r = 0; r < 16; r++) {
                int l = wave * 32 + (r & 3) + 8 * (r >> 2) + 4 * hib;
                float f = A[r];
                ushort_t hi = f2bf(f);
                ushort_t lo = f2bf(f - bf2f(hi));
                out_hi[obase + (size_t)l * 64 + e] = hi;
                out_lo[obase + (size_t)l * 64 + e] = lo;
            }
        }
    } else {
        __syncthreads();   // LDS reuse: all compute reads done
#pragma unroll
        for (int nt = 0; nt < 2; nt++) {
            const int e = nt * 32 + l31;
            const f32x16& A = nt ? acc1 : acc0;
#pragma unroll
            for (int r = 0; r < 16; r++) {
                int l = wave * 32 + (r & 3) + 8 * (r >> 2) + 4 * hib;
                u.T[e][l] = f2bf(A[r]);
            }
        }
        __syncthreads();
        const int e = tid >> 2;
        const int ls = (tid & 3) * 32;
        size_t base = (bh * 64 + e) * NLK + l0 + ls;
#pragma unroll
        for (int c = 0; c < 4; c++)
            *(uint4*)&out_hi[base + c * 8] = *(const uint4*)&u.T[e][ls + c * 8];
    }
}

// ---------------- MFMA flash attention (unchanged from R2).
__global__ __launch_bounds__(256, 3) void attn_kernel(
    const ushort_t* __restrict__ Qhi, const ushort_t* __restrict__ Qlo,
    const ushort_t* __restrict__ Khi, const ushort_t* __restrict__ Klo,
    const ushort_t* __restrict__ Vt,  const float* __restrict__ maskp,
    float* __restrict__ Op) {
    __shared__ ushort_t sKh[64][72];
    __shared__ ushort_t sKl[64][72];
    __shared__ ushort_t sVt[64][72];
    __shared__ float sBs[64];
    __shared__ ushort_t sPs[4][32][72];

    const int tid  = threadIdx.x;
    const int wave = tid >> 6;
    const int lane = tid & 63;
    const int l31  = lane & 31;
    const int hib  = lane >> 5;
    const int h = blockIdx.y, b = blockIdx.z;
    const size_t bh = (size_t)b * NH + h;
    const int q = blockIdx.x * 128 + wave * 32 + l31;

    bf16x8 qh[4], ql[4];
    {
        const ushort_t* ph = Qhi + (bh * NLQ + q) * 64 + hib * 8;
        const ushort_t* pl = Qlo + (bh * NLQ + q) * 64 + hib * 8;
#pragma unroll
        for (int c = 0; c < 4; c++) {
            qh[c] = *(const bf16x8*)(ph + c * 16);
            ql[c] = *(const bf16x8*)(pl + c * 16);
        }
    }

    f32x16 O0, O1;
#pragma unroll
    for (int i = 0; i < 16; i++) { O0[i] = 0.f; O1[i] = 0.f; }
    float mrun = MASKV, lrun = 0.f;

    const int skey = tid >> 2;
    const int se0  = (tid & 3) * 16;

    for (int k0 = 0; k0 < NLK; k0 += 64) {
        __syncthreads();
        {
            const ushort_t* src = Khi + ((bh << 10) + k0 + skey) * 64 + se0;
            *(uint4*)&sKh[skey][se0]     = *(const uint4*)src;
            *(uint4*)&sKh[skey][se0 + 8] = *(const uint4*)(src + 8);
            const ushort_t* srl = Klo + ((bh << 10) + k0 + skey) * 64 + se0;
            *(uint4*)&sKl[skey][se0]     = *(const uint4*)srl;
            *(uint4*)&sKl[skey][se0 + 8] = *(const uint4*)(srl + 8);
            const ushort_t* srv = Vt + ((bh << 6) + skey) * NLK + k0 + se0;
            *(uint4*)&sVt[skey][se0]     = *(const uint4*)srv;
            *(uint4*)&sVt[skey][se0 + 8] = *(const uint4*)(srv + 8);
            if (tid < 64) sBs[tid] = (1.f - maskp[(b << 10) + k0 + tid]) * MASKV;
        }
        __syncthreads();

        f32x16 S0, S1;
#pragma unroll
        for (int i = 0; i < 16; i++) { S0[i] = 0.f; S1[i] = 0.f; }
#pragma unroll
        for (int c = 0; c < 4; c++) {
            bf16x8 ah0 = *(const bf16x8*)&sKh[l31][c * 16 + hib * 8];
            bf16x8 al0 = *(const bf16x8*)&sKl[l31][c * 16 + hib * 8];
            bf16x8 ah1 = *(const bf16x8*)&sKh[32 + l31][c * 16 + hib * 8];
            bf16x8 al1 = *(const bf16x8*)&sKl[32 + l31][c * 16 + hib * 8];
            S0 = __builtin_amdgcn_mfma_f32_32x32x16_bf16(ah0, qh[c], S0, 0, 0, 0);
            S1 = __builtin_amdgcn_mfma_f32_32x32x16_bf16(ah1, qh[c], S1, 0, 0, 0);
            S0 = __builtin_amdgcn_mfma_f32_32x32x16_bf16(ah0, ql[c], S0, 0, 0, 0);
            S1 = __builtin_amdgcn_mfma_f32_32x32x16_bf16(ah1, ql[c], S1, 0, 0, 0);
            S0 = __builtin_amdgcn_mfma_f32_32x32x16_bf16(al0, qh[c], S0, 0, 0, 0);
            S1 = __builtin_amdgcn_mfma_f32_32x32x16_bf16(al1, qh[c], S1, 0, 0, 0);
        }

#pragma unroll
        for (int g = 0; g < 4; g++) {
            float4 b0 = *(const float4*)&sBs[hib * 4 + 8 * g];
            float4 b1 = *(const float4*)&sBs[32 + hib * 4 + 8 * g];
            S0[4 * g + 0] += b0.x; S0[4 * g + 1] += b0.y;
            S0[4 * g + 2] += b0.z; S0[4 * g + 3] += b0.w;
            S1[4 * g + 0] += b1.x; S1[4 * g + 1] += b1.y;
            S1[4 * g + 2] += b1.z; S1[4 * g + 3] += b1.w;
        }

        float mloc = S0[0];
#pragma unroll
        for (int i = 1; i < 16; i++) mloc = fmaxf(mloc, S0[i]);
#pragma unroll
        for (int i = 0; i < 16; i++) mloc = fmaxf(mloc, S1[i]);
        mloc = fmaxf(mloc, __shfl_xor(mloc, 32));
        float newm = fmaxf(mrun, mloc);
        float alpha = __expf(mrun - newm);
        mrun = newm;

        float ls = 0.f;
#pragma unroll
        for (int kh = 0; kh < 2; kh++) {
#pragma unroll
            for (int g = 0; g < 4; g++) {
                float p0, p1, p2, p3;
                if (kh == 0) {
                    p0 = __expf(S0[4 * g + 0] - newm); p1 = __expf(S0[4 * g + 1] - newm);
                    p2 = __expf(S0[4 * g + 2] - newm); p3 = __expf(S0[4 * g + 3] - newm);
                } else {
                    p0 = __expf(S1[4 * g + 0] - newm); p1 = __expf(S1[4 * g + 1] - newm);
                    p2 = __expf(S1[4 * g + 2] - newm); p3 = __expf(S1[4 * g + 3] - newm);
                }
                ls += (p0 + p1) + (p2 + p3);
                uint2 w;
                w.x = (unsigned)f2bf(p0) | ((unsigned)f2bf(p1) << 16);
                w.y = (unsigned)f2bf(p2) | ((unsigned)f2bf(p3) << 16);
                *(uint2*)&sPs[wave][l31][kh * 32 + 8 * g + 4 * hib] = w;
            }
        }
        ls += __shfl_xor(ls, 32);
        lrun = lrun * alpha + ls;
#pragma unroll
        for (int i = 0; i < 16; i++) { O0[i] *= alpha; O1[i] *= alpha; }

#pragma unroll
        for (int c = 0; c < 4; c++) {
            bf16x8 pf = *(const bf16x8*)&sPs[wave][l31][c * 16 + hib * 8];
            bf16x8 v0 = *(const bf16x8*)&sVt[l31][c * 16 + hib * 8];
            bf16x8 v1 = *(const bf16x8*)&sVt[32 + l31][c * 16 + hib * 8];
            O0 = __builtin_amdgcn_mfma_f32_32x32x16_bf16(v0, pf, O0, 0, 0, 0);
            O1 = __builtin_amdgcn_mfma_f32_32x32x16_bf16(v1, pf, O1, 0, 0, 0);
        }
    }

    const float linv = 1.f / lrun;
    float* obase = Op + ((size_t)(b * NLQ + q)) * (NH * 64) + h * 64;
#pragma unroll
    for (int me = 0; me < 2; me++) {
#pragma unroll
        for (int g = 0; g < 4; g++) {
            int e0 = me * 32 + 8 * g + 4 * hib;
            float4 o;
            if (me == 0) {
                o.x = O0[4 * g + 0] * linv; o.y = O0[4 * g + 1] * linv;
                o.z = O0[4 * g + 2] * linv; o.w = O0[4 * g + 3] * linv;
            } else {
                o.x = O1[4 * g + 0] * linv; o.y = O1[4 * g + 1] * linv;
                o.z = O1[4 * g + 2] * linv; o.w = O1[4 * g + 3] * linv;
            }
            *(float4*)&obase[e0] = o;
        }
    }
}

// ---------------- LayerNorm (unchanged).
__global__ __launch_bounds__(256) void ln_kernel(const float* __restrict__ X,
                                                 const float* __restrict__ gamma,
                                                 const float* __restrict__ beta,
                                                 float* __restrict__ out) {
    const int row = blockIdx.x * 4 + (threadIdx.x >> 6);
    const int lane = threadIdx.x & 63;
    const float* x = &X[(size_t)row * 512];
    float4 v0 = *(const float4*)&x[lane * 8];
    float4 v1 = *(const float4*)&x[lane * 8 + 4];
    float sum = v0.x + v0.y + v0.z + v0.w + v1.x + v1.y + v1.z + v1.w;
    float sq = v0.x * v0.x + v0.y * v0.y + v0.z * v0.z + v0.w * v0.w
             + v1.x * v1.x + v1.y * v1.y + v1.z * v1.z + v1.w * v1.w;
#pragma unroll
    for (int off = 32; off > 0; off >>= 1) {
        sum += __shfl_down(sum, off);
        sq  += __shfl_down(sq, off);
    }
    sum = __shfl(sum, 0);
    sq  = __shfl(sq, 0);
    const float mean = sum * (1.f / 512.f);
    const float var = sq * (1.f / 512.f) - mean * mean;
    const float rstd = rsqrtf(var + 1e-14f);
    const float g = gamma[0], be = beta[0];
    float* o = &out[(size_t)row * 512];
    float4 r0, r1;
    r0.x = (v0.x - mean) * rstd * g + be;  r0.y = (v0.y - mean) * rstd * g + be;
    r0.z = (v0.z - mean) * rstd * g + be;  r0.w = (v0.w - mean) * rstd * g + be;
    r1.x = (v1.x - mean) * rstd * g + be;  r1.y = (v1.y - mean) * rstd * g + be;
    r1.z = (v1.z - mean) * rstd * g + be;  r1.w = (v1.w - mean) * rstd * g + be;
    *(float4*)&o[lane * 8] = r0;
    *(float4*)&o[lane * 8 + 4] = r1;
}

extern "C" void kernel_launch(void* const* d_in, const int* in_sizes, int n_in,
                              void* d_out, int out_size, void* d_ws, size_t ws_size,
                              hipStream_t stream) {
    const float* query = (const float*)d_in[0];
    const float* key_t = (const float*)d_in[1];
    const float* value = (const float*)d_in[2];
    const float* mask  = (const float*)d_in[3];
    const float* Wq    = (const float*)d_in[4];
    const float* Wk    = (const float*)d_in[5];
    const float* Wv    = (const float*)d_in[6];
    const float* gamma = (const float*)d_in[7];
    const float* beta  = (const float*)d_in[8];
    float* out = (float*)d_out;

    const size_t A = (size_t)NB * NLQ * ND;        // 4,194,304 (X-sized bf16 buffer)
    const size_t WS = (size_t)NH * 64 * ND;        // 262,144
    ushort_t* Qhi = (ushort_t*)d_ws;
    ushort_t* Qlo = Qhi + A;
    ushort_t* Khi = Qhi + 2 * A;
    ushort_t* Klo = Qhi + 3 * A;
    ushort_t* Vt  = Qhi + 4 * A;
    ushort_t* Xh  = Qhi + 5 * A;
    ushort_t* Xl  = Qhi + 6 * A;
    ushort_t* Wtq_h = Qhi + 7 * A;
    ushort_t* Wtq_l = Wtq_h + WS;
    ushort_t* Wtk_h = Wtq_h + 2 * WS;
    ushort_t* Wtk_l = Wtq_h + 3 * WS;
    ushort_t* Wtv_h = Wtq_h + 4 * WS;
    ushort_t* Wtv_l = Wtq_h + 5 * WS;

    wsplit_kernel<<<dim3(ND / 64, NH, 3), 256, 0, stream>>>(
        Wq, Wk, Wv, Wtq_h, Wtq_l, Wtk_h, Wtk_l, Wtv_h, Wtv_l);

    const int xgrid = (int)(A / (8 * 256));
    dim3 pgrid(NLQ / 128, NH, NB);

    xsplit_kernel<1><<<xgrid, 256, 0, stream>>>(query, Xh, Xl);
    proj_mfma_kernel<3, 0><<<pgrid, 256, 0, stream>>>(Xh, Xl, Wtq_h, Wtq_l, Qhi, Qlo);

    xsplit_kernel<1><<<xgrid, 256, 0, stream>>>(key_t, Xh, Xl);
    proj_mfma_kernel<3, 0><<<pgrid, 256, 0, stream>>>(Xh, Xl, Wtk_h, Wtk_l, Khi, Klo);

    xsplit_kernel<0><<<xgrid, 256, 0, stream>>>(value, Xh, nullptr);
    proj_mfma_kernel<1, 1><<<pgrid, 256, 0, stream>>>(Xh, nullptr, Wtv_h, nullptr, Vt, nullptr);

    dim3 agrid(NLQ / 128, NH, NB);
    attn_kernel<<<agrid, 256, 0, stream>>>(Qhi, Qlo, Khi, Klo, Vt, mask, out);

    ln_kernel<<<(NB * NLQ) / 4, 256, 0, stream>>>(out, gamma, beta, out);
}